// Round 12
// baseline (159.210 us; speedup 1.0000x reference)
//
#include <hip/hip_runtime.h>
#include <hip/hip_bf16.h>

// FeaStNet NeighbourAssignment — 3 launches:
//   k1_pre : ST[i][0:8]=s_i, ST[i][8:16]=exp(t_i) via bf16 MFMA;
//            xbf=bf16(x); WtB=bf16(Wcat^T); rowptr from sorted dst.
//   k3_mfma: one wave per node. 32-edge chunks:
//            q[e][m]=e^{s_m}*et[src[e]][m]/sum (8-lane-group softmax),
//            q(bf16)->qt[16][40] LDS (transposed), x rows->xt[32] rows of
//            STRIDE 66 elements (>=64 so rows don't overlap; 4*66%32==8 so
//            the four q3 quads read disjoint bank octets -> 2 lanes/bank;
//            writes as 4x ds_write_b32, banks (kk+4mm+w)%32 -> 2 lanes/bank),
//            G[16,64] += QT[16,32] @ X[32,64] via 4x mfma 16x16x32 per chunk.
//            Padded slots: q=0, src clamped to a real edge (0*finite=0).
//   k4_mfma: out = (Gbf @ Wcat + R @ b)/8 via bf16 MFMA, W^T tile in LDS.

#define CDIM 64
#define SDIM 8
#define XT_STRIDE 66  // elements; >=64 (row size) and S%8==2 (bank-free)

typedef __bf16 bf16x8 __attribute__((ext_vector_type(8)));
typedef float f32x4 __attribute__((ext_vector_type(4)));

// blocks [0,nbN): ST+xbf via MFMA ; [nbN,nbN+128): WtB ; rest: rowptr
__global__ __launch_bounds__(256) void k1_pre(
    const float* __restrict__ x, const float* __restrict__ Ws,
    const float* __restrict__ bs, const float* __restrict__ Wt,
    const float* __restrict__ bt, const float* __restrict__ W,
    const int* __restrict__ dst, float* __restrict__ ST,
    __hip_bfloat16* __restrict__ xbf, __hip_bfloat16* __restrict__ WtB,
    int* __restrict__ rowptr, int N, int E, int nbN) {
  int bid = blockIdx.x;
  if (bid >= nbN + 128) {  // rowptr build (dst sorted)
    int e = (bid - nbN - 128) * 256 + threadIdx.x;
    if (e >= E) return;
    int a = dst[e];
    int bnd = (e + 1 < E) ? dst[e + 1] : N;
    if (e == 0) {
      for (int d = 0; d <= a; ++d) rowptr[d] = 0;
    }
    for (int d = a + 1; d <= bnd; ++d) rowptr[d] = e + 1;
    return;
  }
  if (bid >= nbN) {  // Wcat[512][64] -> WtB[64][512] bf16
    int t = (bid - nbN) * 256 + threadIdx.x;  // 0..32767
    int o = t >> 9, k = t & 511;
    WtB[t] = __float2bfloat16(W[(size_t)k * 64 + o]);
    return;
  }

  // ---- ST + xbf for 64 nodes via MFMA ----
  __shared__ __hip_bfloat16 wst[16 * 72];  // WstT[n][k], stride 72
  __shared__ float bst[16];
  int t = threadIdx.x;
#pragma unroll
  for (int j = 0; j < 4; ++j) {
    int idx = t * 4 + j;  // 0..1023
    int n = idx >> 6, k = idx & 63;
    float v = (n < 8) ? Ws[k * 8 + n] : Wt[k * 8 + (n - 8)];
    wst[n * 72 + k] = __float2bfloat16(v);
  }
  if (t < 16) bst[t] = (t < 8) ? bs[t] : bt[t - 8];
  __syncthreads();

  int wave = t >> 6, lane = t & 63;
  int r = lane & 15, q = lane >> 4;
  int node = bid * 64 + wave * 16 + r;
  int nodec = node < N ? node : N - 1;
  const float* xr = x + (size_t)nodec * CDIM;

  bf16x8 afrag[2];
#pragma unroll
  for (int kt = 0; kt < 2; ++kt) {
    float4 u0 = *(const float4*)(xr + kt * 32 + q * 8);
    float4 u1 = *(const float4*)(xr + kt * 32 + q * 8 + 4);
    union { bf16x8 v; __hip_bfloat16 h[8]; } a;
    a.h[0] = __float2bfloat16(u0.x); a.h[1] = __float2bfloat16(u0.y);
    a.h[2] = __float2bfloat16(u0.z); a.h[3] = __float2bfloat16(u0.w);
    a.h[4] = __float2bfloat16(u1.x); a.h[5] = __float2bfloat16(u1.y);
    a.h[6] = __float2bfloat16(u1.z); a.h[7] = __float2bfloat16(u1.w);
    afrag[kt] = a.v;
    if (node < N)
      *(bf16x8*)(xbf + (size_t)node * CDIM + kt * 32 + q * 8) = a.v;
  }

  bf16x8 bf0 = *(const bf16x8*)(wst + r * 72 + q * 8);
  bf16x8 bf1 = *(const bf16x8*)(wst + r * 72 + 32 + q * 8);

  f32x4 acc = {0, 0, 0, 0};
  acc = __builtin_amdgcn_mfma_f32_16x16x32_bf16(afrag[0], bf0, acc, 0, 0, 0);
  acc = __builtin_amdgcn_mfma_f32_16x16x32_bf16(afrag[1], bf1, acc, 0, 0, 0);

  int m = lane & 15;
#pragma unroll
  for (int v = 0; v < 4; ++v) {
    int nd = bid * 64 + wave * 16 + q * 4 + v;
    if (nd >= N) continue;
    float val = acc[v] + bst[m];
    if (m >= 8) val = __expf(val);  // store exp(t)
    ST[nd * 16 + m] = val;
  }
}

// One wave per node; 32-edge chunks through MFMA.
// MFMA layouts (gfx950 16x16x32 bf16, m89/m120-verified):
//   A: a[j]=A[lane&15][(lane>>4)*8+j] ; B: b[j]=B[(lane>>4)*8+j][lane&15]
//   D: reg v -> row=(lane>>4)*4+v, col=lane&15
__global__ __launch_bounds__(256) void k3_mfma(
    const __hip_bfloat16* __restrict__ xbf, const int* __restrict__ src,
    const int* __restrict__ rowptr, const float* __restrict__ ST,
    __hip_bfloat16* __restrict__ Gbf, float* __restrict__ R, int N) {
  __shared__ __hip_bfloat16 qt_s[4][16 * 40];          // [wave][m'][k], stride 40
  __shared__ __hip_bfloat16 xt_s[4][32 * XT_STRIDE];   // [wave][e][c], stride 66

  int wave = threadIdx.x >> 6;
  int lane = threadIdx.x & 63;
  int i = blockIdx.x * 4 + wave;
  if (i >= N) return;  // wave-private LDS, no barriers

  int mm = lane & 7;   // m for softmax / channel-chunk for gather
  int kk = lane >> 3;  // edge-in-group for softmax & gather
  int mp = lane & 15;  // MFMA row/col
  int q3 = lane >> 4;  // MFMA quad

  __hip_bfloat16* qt = &qt_s[wave][0];
  __hip_bfloat16* xt = &xt_s[wave][0];

  // zero qt rows 8..15 once (A rows 8-15 -> D rows 8-15 = 0, never stored)
  __hip_bfloat16 z0 = __float2bfloat16(0.0f);
#pragma unroll
  for (int z = 0; z < 5; ++z) qt[320 + z * 64 + lane] = z0;

  int lo = rowptr[i];
  int hi = rowptr[i + 1];
  float uv = __expf(ST[i * 16 + mm]);  // e^{s_m}

  f32x4 acc0 = {0, 0, 0, 0}, acc1 = {0, 0, 0, 0};
  f32x4 acc2 = {0, 0, 0, 0}, acc3 = {0, 0, 0, 0};
  float racc = 0.f;

  if (lo < hi) {
    int ecl = hi - 1;
    int iv[4];
#pragma unroll
    for (int g = 0; g < 4; ++g) {
      int ek = lo + g * 8 + kk;
      iv[g] = src[ek < ecl ? ek : ecl];
    }

    for (int c0 = lo; c0 < hi; c0 += 32) {
      // x-gathers: lane loads 16B of its own edge's row (8 rows per instr)
      bf16x8 xv[4];
#pragma unroll
      for (int g = 0; g < 4; ++g)
        xv[g] = *(const bf16x8*)(xbf + (size_t)iv[g] * CDIM + mm * 8);

      // e^t gathers for softmax
      float tv[4];
#pragma unroll
      for (int g = 0; g < 4; ++g) tv[g] = ST[iv[g] * 16 + 8 + mm];

      // prefetch next chunk's src indices
      int nc0 = c0 + 32;
      int niv[4];
#pragma unroll
      for (int g = 0; g < 4; ++g) {
        int ek = nc0 + g * 8 + kk;
        ek = ek < ecl ? ek : ecl;
        niv[g] = (nc0 < hi) ? src[ek] : iv[g];
      }

      // softmax per 8-edge group; q -> qt (transposed, bf16)
#pragma unroll
      for (int g = 0; g < 4; ++g) {
        float w = uv * tv[g];
        float ssum = w + __shfl_xor(w, 1);
        ssum += __shfl_xor(ssum, 2);
        ssum += __shfl_xor(ssum, 4);
        float qv = w * __frcp_rn(ssum);
        if (c0 + g * 8 + kk >= hi) qv = 0.f;  // padded slot
        racc += qv;
        qt[mm * 40 + g * 8 + kk] = __float2bfloat16(qv);
      }

      // x rows -> xt[e][c], stride 66: 4 dword writes per row segment
      // (banks (33kk+4mm+w)%32 == (kk+4mm+w)%32 -> exactly 2 lanes/bank)
#pragma unroll
      for (int g = 0; g < 4; ++g) {
        union { bf16x8 v; int w[4]; } u;
        u.v = xv[g];
        __hip_bfloat16* xp = xt + (g * 8 + kk) * XT_STRIDE + mm * 8;
#pragma unroll
        for (int w = 0; w < 4; ++w) *(int*)(xp + w * 2) = u.w[w];
      }

      // A-frag: one contiguous b128 from qt
      bf16x8 afrag = *(const bf16x8*)(qt + mp * 40 + q3 * 8);

      // B-frags: u16 reads from xt; stride 66 -> bank ≡ 8*q3 + j + mp/2,
      // four q3 quads on disjoint bank octets, 2 lanes/bank
      {
        union { bf16x8 v; __hip_bfloat16 h[8]; } b0, b1, b2, b3;
#pragma unroll
        for (int j = 0; j < 8; ++j) {
          const __hip_bfloat16* xr = xt + (q3 * 8 + j) * XT_STRIDE + mp;
          b0.h[j] = xr[0];
          b1.h[j] = xr[16];
          b2.h[j] = xr[32];
          b3.h[j] = xr[48];
        }
        acc0 = __builtin_amdgcn_mfma_f32_16x16x32_bf16(afrag, b0.v, acc0, 0, 0, 0);
        acc1 = __builtin_amdgcn_mfma_f32_16x16x32_bf16(afrag, b1.v, acc1, 0, 0, 0);
        acc2 = __builtin_amdgcn_mfma_f32_16x16x32_bf16(afrag, b2.v, acc2, 0, 0, 0);
        acc3 = __builtin_amdgcn_mfma_f32_16x16x32_bf16(afrag, b3.v, acc3, 0, 0, 0);
      }

      iv[0] = niv[0]; iv[1] = niv[1]; iv[2] = niv[2]; iv[3] = niv[3];
    }
  }

  // G write: D reg v -> row m=q3*4+v (keep m<8), col mp, tile t
  if (q3 < 2) {
    __hip_bfloat16* Gi = Gbf + (size_t)i * 512;
#pragma unroll
    for (int v = 0; v < 4; ++v) {
      int m = q3 * 4 + v;
      Gi[m * 64 + 0 + mp]  = __float2bfloat16(acc0[v]);
      Gi[m * 64 + 16 + mp] = __float2bfloat16(acc1[v]);
      Gi[m * 64 + 32 + mp] = __float2bfloat16(acc2[v]);
      Gi[m * 64 + 48 + mp] = __float2bfloat16(acc3[v]);
    }
  }

  racc += __shfl_xor(racc, 8);
  racc += __shfl_xor(racc, 16);
  racc += __shfl_xor(racc, 32);
  if (lane < 8) R[(size_t)i * 8 + lane] = racc;
}

// out[N,64] = (Gbf[N,512] @ Wcat[512,64] + R[N,8] @ b[8,64]) / 8 via bf16 MFMA.
__global__ __launch_bounds__(256) void k4_mfma(
    const __hip_bfloat16* __restrict__ Gbf, const float* __restrict__ R,
    const __hip_bfloat16* __restrict__ WtB, const float* __restrict__ bias,
    float* __restrict__ out, int N) {
  __shared__ float4 btile[64 * 65];  // [n][k] bf16, row = 520 bf16 = 65 float4
  {
    const float4* srcp = (const float4*)WtB;  // 4096 float4
    int t = threadIdx.x;
#pragma unroll
    for (int j = 0; j < 16; ++j) {
      int ci = t + j * 256;
      btile[(ci >> 6) * 65 + (ci & 63)] = srcp[ci];
    }
  }
  __syncthreads();

  int wave = threadIdx.x >> 6;
  int lane = threadIdx.x & 63;
  int r0 = (blockIdx.x * 4 + wave) * 16;
  if (r0 >= N) return;

  int m = lane & 15;
  int q = lane >> 4;
  const __bf16* abase = (const __bf16*)(Gbf + (size_t)(r0 + m) * 512) + q * 8;
  const __bf16* lbase = (const __bf16*)btile + (size_t)m * 520 + q * 8;

  f32x4 acc0 = {0, 0, 0, 0}, acc1 = {0, 0, 0, 0};
  f32x4 acc2 = {0, 0, 0, 0}, acc3 = {0, 0, 0, 0};
#pragma unroll
  for (int kt = 0; kt < 16; ++kt) {
    bf16x8 a = *(const bf16x8*)(abase + kt * 32);
    bf16x8 b0 = *(const bf16x8*)(lbase + 0 * 520 + kt * 32);
    bf16x8 b1 = *(const bf16x8*)(lbase + 16 * 520 + kt * 32);
    bf16x8 b2 = *(const bf16x8*)(lbase + 32 * 520 + kt * 32);
    bf16x8 b3 = *(const bf16x8*)(lbase + 48 * 520 + kt * 32);
    acc0 = __builtin_amdgcn_mfma_f32_16x16x32_bf16(a, b0, acc0, 0, 0, 0);
    acc1 = __builtin_amdgcn_mfma_f32_16x16x32_bf16(a, b1, acc1, 0, 0, 0);
    acc2 = __builtin_amdgcn_mfma_f32_16x16x32_bf16(a, b2, acc2, 0, 0, 0);
    acc3 = __builtin_amdgcn_mfma_f32_16x16x32_bf16(a, b3, acc3, 0, 0, 0);
  }

#pragma unroll
  for (int v = 0; v < 4; ++v) {
    int ri = r0 + q * 4 + v;
    if (ri >= N) continue;
    const float* Ri = R + (size_t)ri * 8;
    float b0s = 0, b1s = 0, b2s = 0, b3s = 0;
#pragma unroll
    for (int mm = 0; mm < 8; ++mm) {
      float rv = Ri[mm];
      b0s = fmaf(rv, bias[mm * 64 + 0 + m], b0s);
      b1s = fmaf(rv, bias[mm * 64 + 16 + m], b1s);
      b2s = fmaf(rv, bias[mm * 64 + 32 + m], b2s);
      b3s = fmaf(rv, bias[mm * 64 + 48 + m], b3s);
    }
    float* orow = out + (size_t)ri * 64;
    orow[0 + m]  = (acc0[v] + b0s) * 0.125f;
    orow[16 + m] = (acc1[v] + b1s) * 0.125f;
    orow[32 + m] = (acc2[v] + b2s) * 0.125f;
    orow[48 + m] = (acc3[v] + b3s) * 0.125f;
  }
}

extern "C" void kernel_launch(void* const* d_in, const int* in_sizes, int n_in,
                              void* d_out, int out_size, void* d_ws, size_t ws_size,
                              hipStream_t stream) {
  const float* x  = (const float*)d_in[0];   // [N,64]
  const int* src  = (const int*)d_in[1];     // [E]
  const int* dst  = (const int*)d_in[2];     // [E] sorted
  const float* W  = (const float*)d_in[3];   // [8,64,64] == Wcat[512,64]
  const float* b  = (const float*)d_in[4];   // [8,64]
  const float* Ws = (const float*)d_in[5];   // [64,8]
  const float* bs = (const float*)d_in[6];   // [8]
  const float* Wt = (const float*)d_in[7];   // [64,8]
  const float* bt = (const float*)d_in[8];   // [8]
  int N = in_sizes[0] / CDIM;
  int E = in_sizes[1];
  float* out = (float*)d_out;

  float* ST = (float*)d_ws;                                      // N*16 f32
  __hip_bfloat16* Gbf = (__hip_bfloat16*)(ST + (size_t)N * 16);  // N*512 bf16
  float* R  = (float*)(Gbf + (size_t)N * 512);                   // N*8 f32
  __hip_bfloat16* WtB = (__hip_bfloat16*)(R + (size_t)N * 8);    // 64*512 bf16
  __hip_bfloat16* xbf = WtB + 64 * 512;                          // N*64 bf16
  int* rowptr = (int*)(xbf + (size_t)N * CDIM);                  // N+1 i32

  int nbN = (N + 63) / 64;
  int nbE = (E + 255) / 256;
  k1_pre<<<nbN + 128 + nbE, 256, 0, stream>>>(x, Ws, bs, Wt, bt, W, dst, ST,
                                              xbf, WtB, rowptr, N, E, nbN);
  k3_mfma<<<(N + 3) / 4, 256, 0, stream>>>(xbf, src, rowptr, ST, Gbf, R, N);
  int mtiles = (N + 15) / 16;
  k4_mfma<<<(mtiles + 3) / 4, 256, 0, stream>>>(Gbf, R, WtB, b, out, N);
}